// Round 6
// baseline (180.003 us; speedup 1.0000x reference)
//
#include <hip/hip_runtime.h>
#include <hip/hip_fp16.h>

typedef unsigned short u16;
typedef unsigned int u32;
typedef __attribute__((ext_vector_type(8))) short bf16x8;
typedef __attribute__((ext_vector_type(4))) float f32x4;

#define NJ 4094

__device__ __forceinline__ u16 f2bf(float f) {
  union { float f; unsigned u; } v;
  v.f = f;
  unsigned r = v.u + 0x7fffu + ((v.u >> 16) & 1u);
  return (u16)(r >> 16);
}

// pack hi16(a),hi16(b) -> u32 (a in low half), with +0x8000 round-half-up pre-added
__device__ __forceinline__ u32 pk_bf(float a, float b) {
  u32 ua = __float_as_uint(a) + 0x8000u;
  u32 ub = __float_as_uint(b) + 0x8000u;
  return __builtin_amdgcn_perm(ub, ua, 0x07060302u);  // bytes: ua.b2,ua.b3,ub.b2,ub.b3
}

// ---------------- dilated conv1d -> x2 (bf16, two layouts, j zero-padded to 4096) ----------------
// 512 blocks (2 b x 256 j-tiles of 16) -> 2 blocks/CU so staging overlaps compute.
// Weight LDS layout i*195 + c*3 + tap: conflict-free staging writes, stride-3 reads (free).
// R13: block 0 zeroes the 64 last-block counters (stream order guarantees visibility to fused).
#define WST 195
template <bool WRITE_OUT>
__global__ __launch_bounds__(256) void conv_kernel(
    const float* __restrict__ x, const float* __restrict__ w,
    const float* __restrict__ bias, u16* __restrict__ x2n, u16* __restrict__ x2T,
    float* __restrict__ out, u32* __restrict__ cnt) {
  __shared__ float xs[64 * 20];      // [in_ch][20 window: j-1 .. j+18]
  __shared__ float wl[64 * WST];     // [in_ch][out_ch*3 + tap], row stride 195 (conflict-free)
  const int b = blockIdx.x >> 8, jt = blockIdx.x & 255;
  const int t = threadIdx.x;
  if (cnt && blockIdx.x == 0 && t < 64) cnt[t] = 0;   // reset last-block counters
  for (int idx = t; idx < 64 * 20; idx += 256) {
    int i = idx / 20, p = idx - i * 20;
    int jg = jt * 16 - 1 + p;          // window starts at j-1
    float v = 0.f;
    if (jg >= 0 && jg < 4096) v = x[(b * 64 + i) * 4096 + jg];
    xs[idx] = v;
  }
  for (int idx = t; idx < 64 * 64 * 3; idx += 256) {
    int c = idx / 192, r = idx - c * 192;   // coalesced read of w[c][i][tap]
    int i = r / 3, tap = r - i * 3;
    wl[i * WST + c * 3 + tap] = w[idx];
  }
  __syncthreads();
  if (WRITE_OUT) {
    for (int idx = t; idx < 64 * 16; idx += 256) {
      int i = idx >> 4, k = idx & 15;
      out[(b * 64 + i) * 4096 + jt * 16 + k] = xs[i * 20 + k + 1];
    }
  }
  const int c = t & 63, jsub = t >> 6;   // each thread: 4 consecutive j
  float bv = bias[c];
  float a0 = bv, a1 = bv, a2 = bv, a3 = bv;
  for (int i = 0; i < 64; i++) {
    const float* wr = &wl[i * WST + c * 3];   // stride-3 read: 2-way max, free
    float w0 = wr[0], w1 = wr[1], w2 = wr[2];
    const float4* xr4 = (const float4*)&xs[i * 20 + jsub * 4];
    float4 xa = xr4[0], xb = xr4[1];
    a0 += w0 * xa.x + w1 * xa.z + w2 * xb.x;
    a1 += w0 * xa.y + w1 * xa.w + w2 * xb.y;
    a2 += w0 * xa.z + w1 * xb.x + w2 * xb.z;
    a3 += w0 * xa.w + w1 * xb.y + w2 * xb.w;
  }
  const int jg0 = jt * 16 + jsub * 4;
  float av[4] = {a0, a1, a2, a3};
  ushort4 hv;
  u16* hp = (u16*)&hv;
#pragma unroll
  for (int k = 0; k < 4; k++) {
    float v = (jg0 + k < NJ) ? av[k] : 0.f;   // zero-pad j=4094,4095
    hp[k] = f2bf(v);
    x2T[(b * 4096 + jg0 + k) * 64 + c] = hp[k];   // coalesced: lanes -> consecutive c
  }
  *(ushort4*)&x2n[(b * 64 + c) * 4096 + jg0] = hv;  // one 8B store (was 8x 2B scattered)
}

// ---------------- fused kernel: R1 structure (kc=0 hoist ONLY) + f16 partials + R13 tail-reduce.
// grid.y=8 (8 j-tiles per block), part = 8 MB; jt loop pinned `#pragma unroll 1`.
// REGISTER CLIFF LEDGER (do not re-trip):
//   R5/R7: full pipeline (unroll + next-jt x2T prefetch)  -> spills, FETCH 9->55 MB, +20 us
//   R2(R9): hoisting BOTH kc of af2 (af2h[2][2], +8 VGPR)  -> spills, FETCH 9->47 MB,
//           WRITE->80 MB, fused 45.5 us, total +13 us.
//   Peak pressure (phase 1): b1(64)+acc(32)+ps(16)+af(8) = 120 + temps ~= the 128 cap
//   (launch_bounds 256,4).  ONLY the kc=0 pair (af2k0[2], 8 VGPR, issued AFTER phase 1)
//   fits.  R13's tail-reduce is EPILOGUE-ONLY (acc dead by then; no loop-pressure change).
//   i-tile 64->32 REJECTED by arithmetic: A-operand L2 demand ~42 TB/s > 34.5 TB/s ceiling.
// Phase 1: wave owns a 16-j strip vs ALL 64 i: D = x2T(A, 4 loads) . x1(B, regs, b=1 negated)
//          -> acc = S0-S1; sigmoid -> P rows to LDS (packed b64).
// Phase 2: D[m=c16][n=i16] = x2n(A, global; kc=0 pre-issued) . P(B, ds_read_b128).
// Epilogue: f16 partial stores; then decoupled last-block-done reduction (rocPRIM pattern):
//   threadfence (release) + device-scope atomicAdd on cnt[i-block]; 8th arriver sums the
//   8 jc partials + x1 -> out for its 64-i strip.  No spinning -> no deadlock; counters
//   reset by conv_kernel (earlier dispatch on same stream).
template <bool ATOMIC>
__global__ __launch_bounds__(256, 4) void fused_kernel(
    const float* __restrict__ x, const u16* __restrict__ x2n_g,
    const u16* __restrict__ x2T_g, u16* __restrict__ part_g,
    float* __restrict__ out, u32* __restrict__ cnt) {
  __shared__ u16 P[2][2 * 64 * 72];   // [buf][b*64 + i_blk][j64 pad 72]
  __shared__ bool lastFlag;
  const int t = threadIdx.x;
  const int wave = t >> 6, lane = t & 63;
  const int q = lane >> 4, ln = lane & 15;
  const int i0 = blockIdx.x * 64;
  const int jc = blockIdx.y;          // j-chunk: 8 tiles of 64

  // block-wide stage x1 -> P[1] as [b][i64][c pad72], b=1 sign-flipped (S0-S1 fold)
  u16* xs = P[1];
#pragma unroll
  for (int rep = 0; rep < 32; rep++) {
    int idx = rep * 256 + t;
    int il = idx & 63, c = (idx >> 6) & 63, b = idx >> 12;
    float v = x[(b * 64 + c) * 4096 + i0 + il];
    if (b) v = -v;
    xs[(b * 64 + il) * 72 + c] = f2bf(v);
  }
  __syncthreads();

  // x1 B-frags for all 4 i-subtiles, both batches: B[k=c][n=i]
  bf16x8 b1[2][4][2];
#pragma unroll
  for (int b = 0; b < 2; b++)
#pragma unroll
    for (int ist = 0; ist < 4; ist++)
#pragma unroll
      for (int kc = 0; kc < 2; kc++)
        b1[b][ist][kc] = *(const bf16x8*)&xs[(b * 64 + ist * 16 + ln) * 72 + kc * 32 + q * 8];

  f32x4 acc[2][4];   // phase-2 accumulators [c-strip][i-strip]
#pragma unroll
  for (int a = 0; a < 2; a++)
#pragma unroll
    for (int bq = 0; bq < 4; bq++) acc[a][bq] = (f32x4){0.f, 0.f, 0.f, 0.f};

  const int b2 = wave >> 1, cs2 = (wave & 1) * 2;  // phase-2 wave assignment

#pragma unroll 1
  for (int jt = jc * 8; jt < jc * 8 + 8; jt++) {
    const int j0 = jt * 64;
    u16* Ps = P[jt & 1];
    // ---- phase 1: wave's 16-j strip x all 64 i; d accumulated with b=1 negated
    f32x4 ps[4];
#pragma unroll
    for (int ist = 0; ist < 4; ist++) ps[ist] = (f32x4){0.f, 0.f, 0.f, 0.f};
#pragma unroll
    for (int b = 0; b < 2; b++)
#pragma unroll
      for (int kc = 0; kc < 2; kc++) {
        bf16x8 af = *(const bf16x8*)&x2T_g[(b * 4096 + j0 + wave * 16 + ln) * 64 + kc * 32 + q * 8];
#pragma unroll
        for (int ist = 0; ist < 4; ist++)
          ps[ist] = __builtin_amdgcn_mfma_f32_16x16x32_bf16(af, b1[b][ist][kc], ps[ist], 0, 0, 0);
      }
    // ---- kc=0 hoist ONLY (8 VGPR; kc=1 too trips the spill cliff, see ledger above)
    bf16x8 af2k0[2];
#pragma unroll
    for (int cst = 0; cst < 2; cst++)
      af2k0[cst] = *(const bf16x8*)&x2n_g[(b2 * 64 + (cs2 + cst) * 16 + ln) * 4096 + j0 + q * 8];
    // ---- sigmoid: p0 = 1/(1+exp(-d)); lane rows j=wave*16+q*4+r, col i=ist*16+ln
#pragma unroll
    for (int ist = 0; ist < 4; ist++) {
      float p0[4], p1[4];
#pragma unroll
      for (int r = 0; r < 4; r++) {
        float e = __expf(-ps[ist][r]);
        p0[r] = __builtin_amdgcn_rcpf(1.f + e);
        p1[r] = 1.f - p0[r];
      }
      uint2 o0 = make_uint2(pk_bf(p0[0], p0[1]), pk_bf(p0[2], p0[3]));
      uint2 o1 = make_uint2(pk_bf(p1[0], p1[1]), pk_bf(p1[2], p1[3]));
      *(uint2*)&Ps[(0 + ist * 16 + ln) * 72 + wave * 16 + q * 4] = o0;    // b=0 rows
      *(uint2*)&Ps[(64 + ist * 16 + ln) * 72 + wave * 16 + q * 4] = o1;   // b=1 rows
    }
    __syncthreads();   // only barrier per j-tile (dbuf covers WAR)
    // ---- phase 2: D[m=c16][n=i16], A = x2n rows (16B global), B = P rows (ds_read_b128)
#pragma unroll
    for (int kc = 0; kc < 2; kc++) {
      bf16x8 af2[2], pb[4];
#pragma unroll
      for (int cst = 0; cst < 2; cst++)
        af2[cst] = (kc == 0)
                       ? af2k0[cst]
                       : *(const bf16x8*)&x2n_g[(b2 * 64 + (cs2 + cst) * 16 + ln) * 4096 + j0 + kc * 32 + q * 8];
#pragma unroll
      for (int ist = 0; ist < 4; ist++)
        pb[ist] = *(const bf16x8*)&Ps[(b2 * 64 + ist * 16 + ln) * 72 + kc * 32 + q * 8];
#pragma unroll
      for (int cst = 0; cst < 2; cst++)
#pragma unroll
        for (int ist = 0; ist < 4; ist++)
          acc[cst][ist] =
              __builtin_amdgcn_mfma_f32_16x16x32_bf16(af2[cst], pb[ist], acc[cst][ist], 0, 0, 0);
    }
  }
  // ---- epilogue (coalesced: consecutive ln -> consecutive ii); f16 partials
#pragma unroll
  for (int cst = 0; cst < 2; cst++)
#pragma unroll
    for (int ist = 0; ist < 4; ist++)
#pragma unroll
      for (int r = 0; r < 4; r++) {
        int c = (cs2 + cst) * 16 + q * 4 + r;
        int ii = i0 + ist * 16 + ln;
        if (ATOMIC) {
          unsafeAtomicAdd(&out[(b2 * 64 + c) * 4096 + ii], acc[cst][ist][r]);
        } else {
          part_g[(((jc * 2 + b2) * 64 + c) << 12) + ii] =
              __half_as_ushort(__float2half(acc[cst][ist][r]));
        }
      }
  if (!ATOMIC) {
    // ---- R13 decoupled last-block reduction for this i-block
    __threadfence();              // release our part stores to agent scope
    __syncthreads();              // all waves' stores precede the count
    if (t == 0) {
      u32 old = __hip_atomic_fetch_add(&cnt[blockIdx.x], 1u, __ATOMIC_ACQ_REL,
                                       __HIP_MEMORY_SCOPE_AGENT);
      lastFlag = (old == 7u);     // 8 jc-blocks per i-block
    }
    __syncthreads();
    if (lastFlag) {
      // out[b][c][i0..i0+63] = x1 + sum_{jc} part[jc][b][c][...]; 2048 float4-quads
#pragma unroll 1
      for (int rep = 0; rep < 8; rep++) {
        int idx = rep * 256 + t;
        int il4 = (idx & 15) * 4, c = (idx >> 4) & 63, b = idx >> 10;
        int gi = (b * 64 + c) * 4096 + i0 + il4;
        float4 s = *(const float4*)&x[gi];
#pragma unroll
        for (int j8 = 0; j8 < 8; j8++) {
          uint2 p = *(const uint2*)&part_g[(((j8 * 2 + b) * 64 + c) << 12) + i0 + il4];
          const __half2* hp = (const __half2*)&p;
          float2 f0 = __half22float2(hp[0]);
          float2 f1 = __half22float2(hp[1]);
          s.x += f0.x; s.y += f0.y; s.z += f1.x; s.w += f1.y;
        }
        *(float4*)&out[gi] = s;
      }
    }
  }
}

extern "C" void kernel_launch(void* const* d_in, const int* in_sizes, int n_in,
                              void* d_out, int out_size, void* d_ws, size_t ws_size,
                              hipStream_t stream) {
  const float* x = (const float*)d_in[0];
  const float* w = (const float*)d_in[1];
  const float* bias = (const float*)d_in[2];
  float* out = (float*)d_out;
  u16* x2n = (u16*)d_ws;                 // [2][64][4096] bf16 = 1 MB
  u16* x2T = x2n + 2 * 64 * 4096;        // [2][4096][64] bf16 = 1 MB
  u16* part = x2T + 2 * 64 * 4096;       // [8][2][64][4096] f16 = 8 MB
  u32* cnt = (u32*)(part + 8u * 2 * 64 * 4096);   // [64] last-block counters

  const size_t need = 2u * 64 * 4096 * 2 * 2 + 8u * 2 * 64 * 4096 * 2 + 64 * 4;
  dim3 grid(64, 8);
  if (ws_size >= need) {
    conv_kernel<false><<<512, 256, 0, stream>>>(x, w, bias, x2n, x2T, out, cnt);
    fused_kernel<false><<<grid, 256, 0, stream>>>(x, x2n, x2T, part, out, cnt);
  } else {
    // fallback: atomic accumulation into out (R4 path)
    conv_kernel<true><<<512, 256, 0, stream>>>(x, w, bias, x2n, x2T, out, nullptr);
    fused_kernel<true><<<grid, 256, 0, stream>>>(x, x2n, x2T, nullptr, out, nullptr);
  }
}

// Round 7
// 100.571 us; speedup vs baseline: 1.7898x; 1.7898x over previous
//
#include <hip/hip_runtime.h>
#include <hip/hip_fp16.h>

typedef unsigned short u16;
typedef unsigned int u32;
typedef __attribute__((ext_vector_type(8))) short bf16x8;
typedef __attribute__((ext_vector_type(4))) float f32x4;

#define NJ 4094

__device__ __forceinline__ u16 f2bf(float f) {
  union { float f; unsigned u; } v;
  v.f = f;
  unsigned r = v.u + 0x7fffu + ((v.u >> 16) & 1u);
  return (u16)(r >> 16);
}

// pack hi16(a),hi16(b) -> u32 (a in low half), with +0x8000 round-half-up pre-added
__device__ __forceinline__ u32 pk_bf(float a, float b) {
  u32 ua = __float_as_uint(a) + 0x8000u;
  u32 ub = __float_as_uint(b) + 0x8000u;
  return __builtin_amdgcn_perm(ub, ua, 0x07060302u);  // bytes: ua.b2,ua.b3,ub.b2,ub.b3
}

// ---------------- dilated conv1d -> x2 (bf16, two layouts, j zero-padded to 4096) ----------------
// 512 blocks (2 b x 256 j-tiles of 16) -> 2 blocks/CU so staging overlaps compute.
// Weight LDS layout i*195 + c*3 + tap: conflict-free staging writes, stride-3 reads (free).
#define WST 195
template <bool WRITE_OUT>
__global__ __launch_bounds__(256) void conv_kernel(
    const float* __restrict__ x, const float* __restrict__ w,
    const float* __restrict__ bias, u16* __restrict__ x2n, u16* __restrict__ x2T,
    float* __restrict__ out) {
  __shared__ float xs[64 * 20];      // [in_ch][20 window: j-1 .. j+18]
  __shared__ float wl[64 * WST];     // [in_ch][out_ch*3 + tap], row stride 195 (conflict-free)
  const int b = blockIdx.x >> 8, jt = blockIdx.x & 255;
  const int t = threadIdx.x;
  for (int idx = t; idx < 64 * 20; idx += 256) {
    int i = idx / 20, p = idx - i * 20;
    int jg = jt * 16 - 1 + p;          // window starts at j-1
    float v = 0.f;
    if (jg >= 0 && jg < 4096) v = x[(b * 64 + i) * 4096 + jg];
    xs[idx] = v;
  }
  for (int idx = t; idx < 64 * 64 * 3; idx += 256) {
    int c = idx / 192, r = idx - c * 192;   // coalesced read of w[c][i][tap]
    int i = r / 3, tap = r - i * 3;
    wl[i * WST + c * 3 + tap] = w[idx];
  }
  __syncthreads();
  if (WRITE_OUT) {
    for (int idx = t; idx < 64 * 16; idx += 256) {
      int i = idx >> 4, k = idx & 15;
      out[(b * 64 + i) * 4096 + jt * 16 + k] = xs[i * 20 + k + 1];
    }
  }
  const int c = t & 63, jsub = t >> 6;   // each thread: 4 consecutive j
  float bv = bias[c];
  float a0 = bv, a1 = bv, a2 = bv, a3 = bv;
  for (int i = 0; i < 64; i++) {
    const float* wr = &wl[i * WST + c * 3];   // stride-3 read: 2-way max, free
    float w0 = wr[0], w1 = wr[1], w2 = wr[2];
    const float4* xr4 = (const float4*)&xs[i * 20 + jsub * 4];
    float4 xa = xr4[0], xb = xr4[1];
    a0 += w0 * xa.x + w1 * xa.z + w2 * xb.x;
    a1 += w0 * xa.y + w1 * xa.w + w2 * xb.y;
    a2 += w0 * xa.z + w1 * xb.x + w2 * xb.z;
    a3 += w0 * xa.w + w1 * xb.y + w2 * xb.w;
  }
  const int jg0 = jt * 16 + jsub * 4;
  float av[4] = {a0, a1, a2, a3};
  ushort4 hv;
  u16* hp = (u16*)&hv;
#pragma unroll
  for (int k = 0; k < 4; k++) {
    float v = (jg0 + k < NJ) ? av[k] : 0.f;   // zero-pad j=4094,4095
    hp[k] = f2bf(v);
    x2T[(b * 4096 + jg0 + k) * 64 + c] = hp[k];   // coalesced: lanes -> consecutive c
  }
  *(ushort4*)&x2n[(b * 64 + c) * 4096 + jg0] = hv;  // one 8B store (was 8x 2B scattered)
}

// ---------------- fused kernel: R1 structure (kc=0 hoist ONLY) + f16 partials (nt stores).
// grid.y=8 (8 j-tiles per block), part = 8 MB; jt loop pinned `#pragma unroll 1`.
// REGISTER CLIFF LEDGER (do not re-trip):
//   R5/R7: full pipeline (unroll + next-jt x2T prefetch)  -> spills, FETCH 9->55 MB, +20 us
//   R2(R9): hoisting BOTH kc of af2 (af2h[2][2], +8 VGPR)  -> spills, FETCH 9->47 MB,
//           WRITE->80 MB, fused 45.5 us, total +13 us.
//   Peak pressure (phase 1): b1(64)+acc(32)+ps(16)+af(8) = 120 + temps ~= the 128 cap
//   (launch_bounds 256,4).  ONLY the kc=0 pair (af2k0[2], 8 VGPR, issued AFTER phase 1) fits.
//   i-tile 64->32 REJECTED by arithmetic: A-operand L2 demand ~42 TB/s > 34.5 TB/s ceiling.
// SYNC-STRUCTURE LEDGER:
//   R6(R13): decoupled last-block-done reduction (threadfence + agent-scope ACQ_REL atomic)
//   -> fused 8->113 us, dur 180.  gfx950 XCD L2s are non-coherent; device-scope release
//   compiles to per-block L2 writeback/invalidate -> 512 serialized cache flushes + loss of
//   x2n/x2T L2 residency.  DO NOT single-kernel the reduction; the separate-dispatch
//   structure pays the device-scope release ONCE at the kernel boundary.
// Phase 1: wave owns a 16-j strip vs ALL 64 i: D = x2T(A, 4 loads) . x1(B, regs, b=1 negated)
//          -> acc = S0-S1; sigmoid -> P rows to LDS (packed b64).
// Phase 2: D[m=c16][n=i16] = x2n(A, global; kc=0 pre-issued) . P(B, ds_read_b128).
// Epilogue: coalesced NONTEMPORAL u16 stores of f16 partials (write-once read-once stream;
// nt keeps x2n/x2T L2-resident).  Partial sums O(+-10): f16 error <=~0.05, negligible.
template <bool ATOMIC>
__global__ __launch_bounds__(256, 4) void fused_kernel(
    const float* __restrict__ x, const u16* __restrict__ x2n_g,
    const u16* __restrict__ x2T_g, u16* __restrict__ part_g,
    float* __restrict__ out) {
  __shared__ u16 P[2][2 * 64 * 72];   // [buf][b*64 + i_blk][j64 pad 72]
  const int t = threadIdx.x;
  const int wave = t >> 6, lane = t & 63;
  const int q = lane >> 4, ln = lane & 15;
  const int i0 = blockIdx.x * 64;
  const int jc = blockIdx.y;          // j-chunk: 8 tiles of 64

  // block-wide stage x1 -> P[1] as [b][i64][c pad72], b=1 sign-flipped (S0-S1 fold)
  u16* xs = P[1];
#pragma unroll
  for (int rep = 0; rep < 32; rep++) {
    int idx = rep * 256 + t;
    int il = idx & 63, c = (idx >> 6) & 63, b = idx >> 12;
    float v = x[(b * 64 + c) * 4096 + i0 + il];
    if (b) v = -v;
    xs[(b * 64 + il) * 72 + c] = f2bf(v);
  }
  __syncthreads();

  // x1 B-frags for all 4 i-subtiles, both batches: B[k=c][n=i]
  bf16x8 b1[2][4][2];
#pragma unroll
  for (int b = 0; b < 2; b++)
#pragma unroll
    for (int ist = 0; ist < 4; ist++)
#pragma unroll
      for (int kc = 0; kc < 2; kc++)
        b1[b][ist][kc] = *(const bf16x8*)&xs[(b * 64 + ist * 16 + ln) * 72 + kc * 32 + q * 8];

  f32x4 acc[2][4];   // phase-2 accumulators [c-strip][i-strip]
#pragma unroll
  for (int a = 0; a < 2; a++)
#pragma unroll
    for (int bq = 0; bq < 4; bq++) acc[a][bq] = (f32x4){0.f, 0.f, 0.f, 0.f};

  const int b2 = wave >> 1, cs2 = (wave & 1) * 2;  // phase-2 wave assignment

#pragma unroll 1
  for (int jt = jc * 8; jt < jc * 8 + 8; jt++) {
    const int j0 = jt * 64;
    u16* Ps = P[jt & 1];
    // ---- phase 1: wave's 16-j strip x all 64 i; d accumulated with b=1 negated
    f32x4 ps[4];
#pragma unroll
    for (int ist = 0; ist < 4; ist++) ps[ist] = (f32x4){0.f, 0.f, 0.f, 0.f};
#pragma unroll
    for (int b = 0; b < 2; b++)
#pragma unroll
      for (int kc = 0; kc < 2; kc++) {
        bf16x8 af = *(const bf16x8*)&x2T_g[(b * 4096 + j0 + wave * 16 + ln) * 64 + kc * 32 + q * 8];
#pragma unroll
        for (int ist = 0; ist < 4; ist++)
          ps[ist] = __builtin_amdgcn_mfma_f32_16x16x32_bf16(af, b1[b][ist][kc], ps[ist], 0, 0, 0);
      }
    // ---- kc=0 hoist ONLY (8 VGPR; kc=1 too trips the spill cliff, see ledger above)
    bf16x8 af2k0[2];
#pragma unroll
    for (int cst = 0; cst < 2; cst++)
      af2k0[cst] = *(const bf16x8*)&x2n_g[(b2 * 64 + (cs2 + cst) * 16 + ln) * 4096 + j0 + q * 8];
    // ---- sigmoid: p0 = 1/(1+exp(-d)); lane rows j=wave*16+q*4+r, col i=ist*16+ln
#pragma unroll
    for (int ist = 0; ist < 4; ist++) {
      float p0[4], p1[4];
#pragma unroll
      for (int r = 0; r < 4; r++) {
        float e = __expf(-ps[ist][r]);
        p0[r] = __builtin_amdgcn_rcpf(1.f + e);
        p1[r] = 1.f - p0[r];
      }
      uint2 o0 = make_uint2(pk_bf(p0[0], p0[1]), pk_bf(p0[2], p0[3]));
      uint2 o1 = make_uint2(pk_bf(p1[0], p1[1]), pk_bf(p1[2], p1[3]));
      *(uint2*)&Ps[(0 + ist * 16 + ln) * 72 + wave * 16 + q * 4] = o0;    // b=0 rows
      *(uint2*)&Ps[(64 + ist * 16 + ln) * 72 + wave * 16 + q * 4] = o1;   // b=1 rows
    }
    __syncthreads();   // only barrier per j-tile (dbuf covers WAR)
    // ---- phase 2: D[m=c16][n=i16], A = x2n rows (16B global), B = P rows (ds_read_b128)
#pragma unroll
    for (int kc = 0; kc < 2; kc++) {
      bf16x8 af2[2], pb[4];
#pragma unroll
      for (int cst = 0; cst < 2; cst++)
        af2[cst] = (kc == 0)
                       ? af2k0[cst]
                       : *(const bf16x8*)&x2n_g[(b2 * 64 + (cs2 + cst) * 16 + ln) * 4096 + j0 + kc * 32 + q * 8];
#pragma unroll
      for (int ist = 0; ist < 4; ist++)
        pb[ist] = *(const bf16x8*)&Ps[(b2 * 64 + ist * 16 + ln) * 72 + kc * 32 + q * 8];
#pragma unroll
      for (int cst = 0; cst < 2; cst++)
#pragma unroll
        for (int ist = 0; ist < 4; ist++)
          acc[cst][ist] =
              __builtin_amdgcn_mfma_f32_16x16x32_bf16(af2[cst], pb[ist], acc[cst][ist], 0, 0, 0);
    }
  }
  // ---- epilogue (coalesced: consecutive ln -> consecutive ii); f16 partials, nt stores
#pragma unroll
  for (int cst = 0; cst < 2; cst++)
#pragma unroll
    for (int ist = 0; ist < 4; ist++)
#pragma unroll
      for (int r = 0; r < 4; r++) {
        int c = (cs2 + cst) * 16 + q * 4 + r;
        int ii = i0 + ist * 16 + ln;
        if (ATOMIC) {
          unsafeAtomicAdd(&out[(b2 * 64 + c) * 4096 + ii], acc[cst][ist][r]);
        } else {
          __builtin_nontemporal_store(
              __half_as_ushort(__float2half(acc[cst][ist][r])),
              &part_g[(((jc * 2 + b2) * 64 + c) << 12) + ii]);
        }
      }
}

// ---------------- out = x1 + sum_{jc} part[jc] (streaming; part f16 nt-loads, accum f32) -----
__global__ __launch_bounds__(256) void reduce_kernel(
    const float4* __restrict__ x, const u16* __restrict__ part,
    float4* __restrict__ out) {
  int i = blockIdx.x * 256 + threadIdx.x;    // over 2*64*4096/4 = 131072 float4
  float4 s = x[i];
#pragma unroll
  for (int jc = 0; jc < 8; jc++) {
    uint2 p;
    p.x = __builtin_nontemporal_load((const u32*)&part[jc * 524288 + 4 * i]);
    p.y = __builtin_nontemporal_load((const u32*)&part[jc * 524288 + 4 * i] + 1);
    const __half2* hp = (const __half2*)&p;
    float2 f0 = __half22float2(hp[0]);
    float2 f1 = __half22float2(hp[1]);
    s.x += f0.x; s.y += f0.y; s.z += f1.x; s.w += f1.y;
  }
  out[i] = s;
}

extern "C" void kernel_launch(void* const* d_in, const int* in_sizes, int n_in,
                              void* d_out, int out_size, void* d_ws, size_t ws_size,
                              hipStream_t stream) {
  const float* x = (const float*)d_in[0];
  const float* w = (const float*)d_in[1];
  const float* bias = (const float*)d_in[2];
  float* out = (float*)d_out;
  u16* x2n = (u16*)d_ws;                 // [2][64][4096] bf16 = 1 MB
  u16* x2T = x2n + 2 * 64 * 4096;        // [2][4096][64] bf16 = 1 MB
  u16* part = x2T + 2 * 64 * 4096;       // [8][2][64][4096] f16 = 8 MB

  const size_t need = 2u * 64 * 4096 * 2 * 2 + 8u * 2 * 64 * 4096 * 2;
  dim3 grid(64, 8);
  if (ws_size >= need) {
    conv_kernel<false><<<512, 256, 0, stream>>>(x, w, bias, x2n, x2T, out);
    fused_kernel<false><<<grid, 256, 0, stream>>>(x, x2n, x2T, part, out);
    reduce_kernel<<<512, 256, 0, stream>>>((const float4*)x, part, (float4*)out);
  } else {
    // fallback: atomic accumulation into out (R4 path)
    conv_kernel<true><<<512, 256, 0, stream>>>(x, w, bias, x2n, x2T, out);
    fused_kernel<true><<<grid, 256, 0, stream>>>(x, x2n, x2T, nullptr, out);
  }
}